// Round 1
// baseline (1105.090 us; speedup 1.0000x reference)
//
#include <hip/hip_runtime.h>

#define DM 256
#define NH 8
#define HD 32
#define BB 8
#define LL 256
#define ROWS (BB*LL)          // 2048
#define SCALE 0.17677669529663687f  // 1/sqrt(32)

// ---------------------------------------------------------------------------
// Kernel 1: QKV projections.  out[row,o] = sum_d in[row,d]*W[o,d] + bias[o]
// grid = (ROWS/32, 3), block = 256.  32 input rows staged in LDS; each thread
// owns one output column o=t and walks W[o,:] (L2-resident, 256KB total).
// ---------------------------------------------------------------------------
__global__ __launch_bounds__(256) void proj_qkv_kernel(
    const float* __restrict__ Q, const float* __restrict__ K, const float* __restrict__ V,
    const float* __restrict__ Wq, const float* __restrict__ bq,
    const float* __restrict__ Wk, const float* __restrict__ bk,
    const float* __restrict__ Wv, const float* __restrict__ bv,
    float* __restrict__ Qp, float* __restrict__ Kp, float* __restrict__ Vp)
{
    const int t   = threadIdx.x;
    const int mat = blockIdx.y;
    const int row0 = blockIdx.x * 32;

    const float* in; const float* W; const float* bias; float* out;
    if (mat == 0)      { in = Q; W = Wq; bias = bq; out = Qp; }
    else if (mat == 1) { in = K; W = Wk; bias = bk; out = Kp; }
    else               { in = V; W = Wv; bias = bv; out = Vp; }

    __shared__ float ins[32 * DM];
    const float4* in4  = (const float4*)(in + (size_t)row0 * DM);
    float4*       ins4 = (float4*)ins;
    #pragma unroll
    for (int i = 0; i < 8; i++) ins4[t + 256 * i] = in4[t + 256 * i];
    __syncthreads();

    float acc[32];
    const float b0 = bias[t];
    #pragma unroll
    for (int r = 0; r < 32; r++) acc[r] = b0;

    const float4* W4 = (const float4*)(W + (size_t)t * DM);
    for (int d4 = 0; d4 < 64; d4++) {
        float4 w = W4[d4];
        #pragma unroll
        for (int r = 0; r < 32; r++) {
            float4 x = ((const float4*)ins)[r * 64 + d4];   // LDS broadcast
            acc[r] += x.x * w.x + x.y * w.y + x.z * w.z + x.w * w.w;
        }
    }
    #pragma unroll
    for (int r = 0; r < 32; r++)
        out[(size_t)(row0 + r) * DM + t] = acc[r];
}

// ---------------------------------------------------------------------------
// Kernel 2: fused time-aware attention for one (b,q) per block.
//   scores[h,k] = scale * sum_j Qp[bq, h*32+j] * (Kp[b,k,h*32+j] + tK[bq,k,h*32+j])
//   p = softmax_k(scores)
//   out[bq, h*32+dd] = sum_k p[h,k] * (Vp[b,k,h*32+dd] + tV[bq,k,h*32+dd])
// Phase A: 8 k-tiles of 32 rows; X = K+tK staged coalesced into LDS (pad 257,
//   2-way bank aliasing = free). HEAD_DIM=32 => each (h,k) dot completes
//   within a tile, no cross-thread reduction.
// Phase B: thread = float4-column, fully coalesced V/tV loads, 4-way LDS reduce.
// ---------------------------------------------------------------------------
__global__ __launch_bounds__(256) void attn_kernel(
    const float* __restrict__ Qp, const float* __restrict__ Kp, const float* __restrict__ Vp,
    const float* __restrict__ tK, const float* __restrict__ tV,
    float* __restrict__ outw)
{
    const int t  = threadIdx.x;
    const int bq = blockIdx.x;            // b*L + q
    const int b  = bq >> 8;

    __shared__ float qs[DM];              // scaled Q row
    __shared__ float Xs[32 * 257];        // staged K+tK tile (padded)
    __shared__ float S[NH * 257];         // scores -> probabilities (padded)
    __shared__ float Ored[4 * DM];        // phase-B partial sums

    qs[t] = Qp[(size_t)bq * DM + t] * SCALE;

    const float* Kb = Kp + (size_t)b  * LL * DM;
    const float* Tb = tK + (size_t)bq * LL * DM;

    const int kk = t & 31;                // k within tile
    const int h  = t >> 5;                // head

    __syncthreads();                      // qs visible
    float qreg[32];
    #pragma unroll
    for (int j = 0; j < 32; j++) qreg[j] = qs[h * HD + j];

    for (int tile = 0; tile < 8; tile++) {
        const float4* K4 = (const float4*)(Kb + (size_t)tile * 32 * DM);
        const float4* T4 = (const float4*)(Tb + (size_t)tile * 32 * DM);
        #pragma unroll
        for (int i = 0; i < 8; i++) {
            int f4 = t + 256 * i;         // float4 index in 32x256 tile
            float4 a = K4[f4];
            float4 c = T4[f4];
            int f = f4 * 4;
            int r = f >> 8;               // tile row 0..31
            int d = f & 255;              // column
            float* dst = &Xs[r * 257 + d];
            dst[0] = a.x + c.x; dst[1] = a.y + c.y;
            dst[2] = a.z + c.z; dst[3] = a.w + c.w;
        }
        __syncthreads();                  // Xs staged

        float s = 0.f;
        const float* xr = &Xs[kk * 257 + h * HD];
        #pragma unroll
        for (int j = 0; j < 32; j++) s += qreg[j] * xr[j];
        S[h * 257 + tile * 32 + kk] = s;
        __syncthreads();                  // compute done before next stage
    }

    // softmax per head: group (h = t>>5, lane kk), width-32 shuffles
    {
        float m = -1e30f;
        #pragma unroll
        for (int j = 0; j < 8; j++) m = fmaxf(m, S[h * 257 + kk + 32 * j]);
        #pragma unroll
        for (int off = 16; off; off >>= 1) m = fmaxf(m, __shfl_xor(m, off, 32));
        float sum = 0.f;
        #pragma unroll
        for (int j = 0; j < 8; j++) sum += __expf(S[h * 257 + kk + 32 * j] - m);
        #pragma unroll
        for (int off = 16; off; off >>= 1) sum += __shfl_xor(sum, off, 32);
        const float inv = 1.0f / sum;
        #pragma unroll
        for (int j = 0; j < 8; j++) {
            int k = kk + 32 * j;
            S[h * 257 + k] = __expf(S[h * 257 + k] - m) * inv;
        }
    }
    __syncthreads();

    // Phase B: thread t -> (c = k-phase 0..3, d4 = float4 column 0..63)
    const int d4 = t & 63;
    const int c  = t >> 6;
    const int hB = d4 >> 3;
    const float4* V4  = (const float4*)(Vp + (size_t)b  * LL * DM);
    const float4* TV4 = (const float4*)(tV + (size_t)bq * LL * DM);
    float4 acc = {0.f, 0.f, 0.f, 0.f};
    for (int i = 0; i < 64; i++) {
        int k = i * 4 + c;
        float p  = S[hB * 257 + k];       // 8 banks, broadcast within groups
        float4 v = V4[(size_t)k * 64 + d4];
        float4 w = TV4[(size_t)k * 64 + d4];
        acc.x += p * (v.x + w.x);
        acc.y += p * (v.y + w.y);
        acc.z += p * (v.z + w.z);
        acc.w += p * (v.w + w.w);
    }
    ((float4*)Ored)[c * 64 + d4] = acc;
    __syncthreads();
    float o = Ored[t] + Ored[DM + t] + Ored[2 * DM + t] + Ored[3 * DM + t];
    outw[(size_t)bq * DM + t] = o;
}

// ---------------------------------------------------------------------------
// Kernel 3: output projection.  out[row,o] = sum_d X[row,d]*Wo[o,d] + bo[o]
// ---------------------------------------------------------------------------
__global__ __launch_bounds__(256) void proj_o_kernel(
    const float* __restrict__ X, const float* __restrict__ Wo,
    const float* __restrict__ bo, float* __restrict__ out)
{
    const int t    = threadIdx.x;
    const int row0 = blockIdx.x * 32;

    __shared__ float ins[32 * DM];
    const float4* in4  = (const float4*)(X + (size_t)row0 * DM);
    float4*       ins4 = (float4*)ins;
    #pragma unroll
    for (int i = 0; i < 8; i++) ins4[t + 256 * i] = in4[t + 256 * i];
    __syncthreads();

    float acc[32];
    const float b0 = bo[t];
    #pragma unroll
    for (int r = 0; r < 32; r++) acc[r] = b0;

    const float4* W4 = (const float4*)(Wo + (size_t)t * DM);
    for (int d4 = 0; d4 < 64; d4++) {
        float4 w = W4[d4];
        #pragma unroll
        for (int r = 0; r < 32; r++) {
            float4 x = ((const float4*)ins)[r * 64 + d4];
            acc[r] += x.x * w.x + x.y * w.y + x.z * w.z + x.w * w.w;
        }
    }
    #pragma unroll
    for (int r = 0; r < 32; r++)
        out[(size_t)(row0 + r) * DM + t] = acc[r];
}

extern "C" void kernel_launch(void* const* d_in, const int* in_sizes, int n_in,
                              void* d_out, int out_size, void* d_ws, size_t ws_size,
                              hipStream_t stream) {
    const float* Q   = (const float*)d_in[0];
    const float* K   = (const float*)d_in[1];
    const float* V   = (const float*)d_in[2];
    const float* tK  = (const float*)d_in[3];
    const float* tV  = (const float*)d_in[4];
    const float* Wq  = (const float*)d_in[5];
    const float* bq  = (const float*)d_in[6];
    const float* Wk  = (const float*)d_in[7];
    const float* bk  = (const float*)d_in[8];
    const float* Wv  = (const float*)d_in[9];
    const float* bv  = (const float*)d_in[10];
    const float* Wo  = (const float*)d_in[11];
    const float* bo  = (const float*)d_in[12];
    float* out = (float*)d_out;

    float* ws = (float*)d_ws;
    float* Qp = ws;
    float* Kp = ws + (size_t)ROWS * DM;
    float* Vp = ws + (size_t)2 * ROWS * DM;
    float* AO = ws + (size_t)3 * ROWS * DM;

    proj_qkv_kernel<<<dim3(ROWS / 32, 3), 256, 0, stream>>>(
        Q, K, V, Wq, bq, Wk, bk, Wv, bv, Qp, Kp, Vp);
    attn_kernel<<<ROWS, 256, 0, stream>>>(Qp, Kp, Vp, tK, tV, AO);
    proj_o_kernel<<<ROWS / 32, 256, 0, stream>>>(AO, Wo, bo, out);
}